// Round 10
// baseline (181.553 us; speedup 1.0000x reference)
//
#include <hip/hip_runtime.h>

// RoiCut: out[i, c, y, x] = fm[assoc[i], c, y0_i + y, x0_i + x]
// fm: [8, 256, 200, 200] fp32, boxes_yx: [512, 2] int32 (y0, x0), assoc: [512] int32
// out: [512, 256, 32, 32] fp32
//
// R9 strategy: true read||store overlap via global_load_lds + counted vmcnt.
//  - block = (sample, channel), 512 thr, LDS = 2 x 40,960 B quarter buffers
//    (81,920 B -> exactly 2 blocks/CU). 4 quarter-phases per block.
//  - per phase k: [s_barrier][issue 5 gload_lds for Q(k+1) -> other buf]
//    [s_waitcnt vmcnt(5)][s_barrier][box store loop on Qk].
//    vmcnt retires in issue order (m135): vmcnt(5) proves Qk's loads AND all
//    older stores done while Q(k+1)'s 5 loads keep streaming during the store
//    loop -> reads and writes are concurrently in flight; no vmcnt(0) drain
//    in the main loop (R3-R8's __syncthreads drain was the ~36 us wall).
//  - boxes binned per (sample, quarter) with straddler duplication + row
//    predication (each output row written exactly once).
//  - R8's rot-XOR bank-conflict-free LDS reads; non-temporal dwordx4 stores.

typedef float v4f __attribute__((ext_vector_type(4)));

constexpr int C_     = 256;
constexpr int H_     = 200;
constexpr int W_     = 200;
constexpr int BOX_   = 32;
constexpr int N_     = 512;
constexpr int B_     = 8;
constexpr int PLANE  = H_ * W_;        // 40000 floats
constexpr int QROWS  = 50;             // rows per quarter-phase
constexpr int NQ     = 4;
constexpr int NBIN   = B_ * NQ;        // 32 (sample, quarter) bins
constexpr int QFLT   = QROWS * W_;     // 10000 floats = 40,000 B per quarter
constexpr int BUFFLT = 10240;          // padded buffer floats (40,960 B)

__global__ __launch_bounds__(512) void group_boxes_kernel(
    const int* __restrict__ boxes,
    const int* __restrict__ assoc,
    unsigned int* __restrict__ keys,
    int* __restrict__ starts)
{
    __shared__ int cnt[NBIN];
    __shared__ int base[NBIN + 1];
    int t = threadIdx.x;   // 512 threads, one per box

    if (t < NBIN) cnt[t] = 0;
    __syncthreads();

    int y0 = boxes[2 * t];
    int x0 = boxes[2 * t + 1];
    y0 = min(max(y0, 0), H_ - BOX_);
    x0 = min(max(x0, 0), W_ - BOX_);
    int a = assoc[t];
    // key: [y0:8 | x0:8 | idx:9]
    unsigned int key = ((unsigned int)y0 << 17) | ((unsigned int)x0 << 9) | (unsigned int)t;

    int q0 = y0 / QROWS;                  // first quarter touched
    int q1 = (y0 + BOX_ - 1) / QROWS;     // last quarter touched (q0 or q0+1)
    int bin0 = a * NQ + q0;
    int p0 = atomicAdd(&cnt[bin0], 1);    // order nondeterminism benign (disjoint outputs)
    int bin1 = -1, p1 = -1;
    if (q1 != q0) {
        bin1 = a * NQ + q1;
        p1 = atomicAdd(&cnt[bin1], 1);
    }
    __syncthreads();

    if (t == 0) {
        int s = 0;
        for (int i = 0; i < NBIN; ++i) { base[i] = s; s += cnt[i]; }
        base[NBIN] = s;
    }
    __syncthreads();

    keys[base[bin0] + p0] = key;
    if (p1 >= 0) keys[base[bin1] + p1] = key;
    if (t <= NBIN) starts[t] = base[t];
}

static __device__ __forceinline__ void gload16(const float* g, float* l) {
    __builtin_amdgcn_global_load_lds(
        (const __attribute__((address_space(1))) void*)g,
        (__attribute__((address_space(3))) void*)l,
        16, 0, 0);
}

__global__ __launch_bounds__(512) void roicut_kernel(
    const float* __restrict__ fm,
    const unsigned int* __restrict__ keys,
    const int* __restrict__ starts,
    float* __restrict__ out)
{
    extern __shared__ float lds[];   // 2 x 10240 floats = 81,920 B

    int bid  = blockIdx.x;
    int c    = bid & 255;            // channel
    int a    = bid >> 8;             // sample
    int t    = threadIdx.x;          // 512 threads = 8 waves
    int w    = t >> 6;               // wave id 0..7
    int lane = t & 63;

    const float* plane = fm + (size_t)(a * C_ + c) * PLANE;

    int segf = w * 1280;             // wave's segment base within a quarter (floats)
    int lo4  = lane * 4;             // lane's float offset within a 1 KB chunk

    // stage quarter q into buffer buf (each wave issues EXACTLY 5 gload_lds)
    auto stage = [&](int q, int buf) {
        const float* qb = plane + q * QFLT;
        float*       lb = lds + buf * BUFFLT;
        if (w < 7) {
            #pragma unroll
            for (int i = 0; i < 5; ++i)
                gload16(qb + segf + i * 256 + lo4, lb + segf + i * 256);
        } else {
            #pragma unroll
            for (int i = 0; i < 4; ++i)
                gload16(qb + segf + i * 256 + lo4, lb + segf + i * 256);
            // ragged tail: quarter = 10000 floats; wave 7 covers [8960,10000).
            // 5th load covers [9984,10000); lanes >=4 clamp to the last 16 B
            // (their LDS bytes land in the [40000,40960) pad, never read).
            int off = lo4 > 12 ? 12 : lo4;
            gload16(qb + 9984 + off, lb + 9984);
        }
    };

    // box-loop geometry
    int sub = t >> 8;                // 0..1: 2 boxes in flight (4 waves each)
    int q   = t & 255;               // pixel-quad within box tile
    int y   = q >> 3;                // 0..31
    int xg  = (q & 7) << 2;          // 0,4,...,28
    int rot = y & 3;                 // per-row XOR rotation (bank spreading)

    // prologue: issue Q0
    stage(0, 0);

    for (int k = 0; k < NQ; ++k) {
        // all waves finished reading buf (k+1)&1 (phase k-1) -> safe to overwrite
        __builtin_amdgcn_sched_barrier(0);
        __builtin_amdgcn_s_barrier();

        if (k < NQ - 1) {
            stage(k + 1, (k + 1) & 1);
            asm volatile("s_waitcnt vmcnt(5)" ::: "memory");   // Qk loads + older stores done
        } else {
            asm volatile("s_waitcnt vmcnt(0)" ::: "memory");   // last phase: full drain
        }
        __builtin_amdgcn_sched_barrier(0);
        __builtin_amdgcn_s_barrier();    // buf k&1 ready for all waves

        // ---- store loop for quarter k ----
        int bin = a * NQ + k;
        int b0 = starts[bin], b1 = starts[bin + 1];
        const float* lb = lds + (k & 1) * BUFFLT;
        int rbase = k * QROWS;

        for (int b = b0; b < b1; b += 2) {
            int bb = b + sub;
            if (bb < b1) {
                unsigned int v = keys[bb];
                int y0 = (v >> 17) & 255;
                int x0 = (v >> 9) & 255;
                int i  = (int)(v & 511u);
                int ly = y0 + y - rbase;          // row within this quarter
                if (ly >= 0 && ly < QROWS) {      // predicated (straddling boxes)
                    const float* p = lb + ly * W_ + (x0 + xg);
                    // XOR-rotated reads: 32 banks x 2-way -> conflict-free (m136)
                    v4f vv;
                    vv[0] = p[0 ^ rot];
                    vv[1] = p[1 ^ rot];
                    vv[2] = p[2 ^ rot];
                    vv[3] = p[3 ^ rot];
                    v4f s1 = { vv[1], vv[0], vv[3], vv[2] };
                    vv = (rot & 1) ? s1 : vv;
                    v4f s2 = { vv[2], vv[3], vv[0], vv[1] };
                    vv = (rot & 2) ? s2 : vv;
                    v4f* dst = (v4f*)(out + (((size_t)i << 18) + ((size_t)c << 10) + (size_t)(q << 2)));
                    __builtin_nontemporal_store(vv, dst);
                }
            }
        }
    }
}

extern "C" void kernel_launch(void* const* d_in, const int* in_sizes, int n_in,
                              void* d_out, int out_size, void* d_ws, size_t ws_size,
                              hipStream_t stream) {
    const float* fm    = (const float*)d_in[0];
    const int*   boxes = (const int*)d_in[1];
    const int*   assoc = (const int*)d_in[2];
    float*       out   = (float*)d_out;

    unsigned int* keys   = (unsigned int*)d_ws;          // <= 1024 u32
    int*          starts = (int*)d_ws + 2 * N_;          // 33 ints

    // allow 81,920 B dynamic LDS (host-side attribute; idempotent, no stream op)
    (void)hipFuncSetAttribute((const void*)roicut_kernel,
                              hipFuncAttributeMaxDynamicSharedMemorySize,
                              2 * BUFFLT * (int)sizeof(float));

    group_boxes_kernel<<<1, N_, 0, stream>>>(boxes, assoc, keys, starts);

    int grid = B_ * C_;   // 2048 blocks: one per (sample, channel)
    roicut_kernel<<<grid, 512, 2 * BUFFLT * sizeof(float), stream>>>(fm, keys, starts, out);
}

// Round 11
// 177.144 us; speedup vs baseline: 1.0249x; 1.0249x over previous
//
#include <hip/hip_runtime.h>

// RoiCut: out[i, c, y, x] = fm[assoc[i], c, y0_i + y, x0_i + x]
// fm: [8, 256, 200, 200] fp32, boxes_yx: [512, 2] int32 (y0, x0), assoc: [512] int32
// out: [512, 256, 32, 32] fp32
//
// R10 strategy: exact A/B on R8 (best, 168.9 us) — ONLY change:
//   __builtin_nontemporal_store -> plain store.
//  Rationale: nt stores bypass L2 write-combining; the harness's fill kernel
//  sustains 6.7-6.8 TB/s write-only through the normal L2 path. In this
//  structure reads are register-staged to LDS exactly once, so there is no
//  read working set in L2 for stores to evict -> nt has no upside here, and
//  its per-byte cost was never isolated (bundled in since R2).
//  Everything else identical to R8: half-plane blocks (80,000 B LDS, 2/CU),
//  exact-once coalesced staging, rot-XOR conflict-free LDS reads,
//  counting-scatter grouping.

typedef float v4f __attribute__((ext_vector_type(4)));

constexpr int C_     = 256;
constexpr int H_     = 200;
constexpr int W_     = 200;
constexpr int BOX_   = 32;
constexpr int N_     = 512;
constexpr int B_     = 8;
constexpr int PLANE  = H_ * W_;       // 40000 floats
constexpr int HROWS  = 100;           // rows per half
constexpr int HLDS   = HROWS * W_;    // 20000 floats = 80,000 B
constexpr int HLDS4  = HLDS / 4;      // 5000 float4

__global__ __launch_bounds__(512) void group_boxes_kernel(
    const int* __restrict__ boxes,
    const int* __restrict__ assoc,
    unsigned int* __restrict__ keys,
    int* __restrict__ starts)
{
    __shared__ int cnt[B_];
    __shared__ int base[B_ + 1];
    int t = threadIdx.x;   // 512 threads, one per box

    if (t < B_) cnt[t] = 0;
    __syncthreads();

    int y0 = boxes[2 * t];
    int x0 = boxes[2 * t + 1];
    y0 = min(max(y0, 0), H_ - BOX_);
    x0 = min(max(x0, 0), W_ - BOX_);
    int a = assoc[t];
    int pos = atomicAdd(&cnt[a], 1);   // order nondeterminism benign (disjoint outputs)
    __syncthreads();

    if (t == 0) {
        int s = 0;
        for (int i = 0; i < B_; ++i) { base[i] = s; s += cnt[i]; }
        base[B_] = s;
    }
    __syncthreads();

    // key: [y0:8 | x0:8 | idx:9]
    keys[base[a] + pos] = ((unsigned int)y0 << 17) | ((unsigned int)x0 << 9) | (unsigned int)t;
    if (t <= B_) starts[t] = base[t];
}

__global__ __launch_bounds__(1024, 8) void roicut_kernel(
    const float* __restrict__ fm,
    const unsigned int* __restrict__ keys,
    const int* __restrict__ starts,
    float* __restrict__ out)
{
    extern __shared__ float lds[];   // 80,000 B = half plane (100 rows x 200)

    int bid = blockIdx.x;
    int h = bid & 1;                 // half: rows [100h, 100h+100)
    int c = (bid >> 1) & 255;        // channel
    int a = bid >> 9;                // sample
    int t = threadIdx.x;             // 1024 threads

    // ---- stage half plane into LDS (canonical conflict-free b128 pattern) ----
    const v4f* src = (const v4f*)(fm + (size_t)(a * C_ + c) * PLANE) + h * HLDS4;
    v4f* l4 = (v4f*)lds;
    v4f r0 = src[t];
    v4f r1 = src[t + 1024];
    v4f r2 = src[t + 2048];
    v4f r3 = src[t + 3072];
    bool tail = t < (HLDS4 - 4096);   // t < 904
    v4f r4;
    if (tail) r4 = src[t + 4096];
    l4[t]        = r0;
    l4[t + 1024] = r1;
    l4[t + 2048] = r2;
    l4[t + 3072] = r3;
    if (tail) l4[t + 4096] = r4;
    __syncthreads();

    // ---- box loop: 4 boxes in flight (sub = 4 waves each) ----
    int b0 = starts[a], b1 = starts[a + 1];
    int sub = t >> 8;             // 0..3
    int q   = t & 255;            // pixel-quad within box tile
    int y   = q >> 3;             // 0..31
    int xg  = (q & 7) << 2;       // 0,4,...,28
    int rot = y & 3;              // per-row XOR rotation for bank spreading
    int hbase = h * HROWS;        // first plane row owned by this half

    for (int b = b0; b < b1; b += 4) {
        int bb = b + sub;
        if (bb < b1) {
            unsigned int v = keys[bb];
            int y0 = (v >> 17) & 255;
            int x0 = (v >> 9) & 255;
            int i  = (int)(v & 511u);
            int ly = y0 + y - hbase;          // row within this half
            if (ly >= 0 && ly < HROWS) {      // predicated rows (straddling boxes)
                const float* p = lds + ly * W_ + (x0 + xg);
                // XOR-rotated reads: instruction m touches element (m ^ rot);
                // per instruction, lanes cover 32 banks at 2-way -> conflict-free.
                v4f vv;
                vv[0] = p[0 ^ rot];
                vv[1] = p[1 ^ rot];
                vv[2] = p[2 ^ rot];
                vv[3] = p[3 ^ rot];
                // un-rotate: out[d] = vv[d ^ rot], via two conditional swaps
                v4f s1 = { vv[1], vv[0], vv[3], vv[2] };   // xor-by-1 shuffle
                vv = (rot & 1) ? s1 : vv;
                v4f s2 = { vv[2], vv[3], vv[0], vv[1] };   // xor-by-2 shuffle
                vv = (rot & 2) ? s2 : vv;
                // R10 A/B: plain store (was __builtin_nontemporal_store)
                *reinterpret_cast<v4f*>(out + (((size_t)i << 18) + ((size_t)c << 10) + (size_t)(q << 2))) = vv;
            }
        }
    }
}

extern "C" void kernel_launch(void* const* d_in, const int* in_sizes, int n_in,
                              void* d_out, int out_size, void* d_ws, size_t ws_size,
                              hipStream_t stream) {
    const float* fm    = (const float*)d_in[0];
    const int*   boxes = (const int*)d_in[1];
    const int*   assoc = (const int*)d_in[2];
    float*       out   = (float*)d_out;

    unsigned int* keys   = (unsigned int*)d_ws;        // 512 u32
    int*          starts = (int*)d_ws + N_;            // 9 ints

    // allow 80,000 B dynamic LDS (host-side attribute; idempotent, no stream op)
    (void)hipFuncSetAttribute((const void*)roicut_kernel,
                              hipFuncAttributeMaxDynamicSharedMemorySize,
                              HLDS * (int)sizeof(float));

    group_boxes_kernel<<<1, N_, 0, stream>>>(boxes, assoc, keys, starts);

    int grid = B_ * C_ * 2;   // 4096 blocks: one per (sample, channel, half)
    roicut_kernel<<<grid, 1024, HLDS * sizeof(float), stream>>>(fm, keys, starts, out);
}